// Round 1
// baseline (27548.666 us; speedup 1.0000x reference)
//
#include <hip/hip_runtime.h>

// ---------------- problem constants ----------------
// B=512, T=128, H=512, ZT=64, GRU_IN=579
// groups: 16 groups x 32 rows; slices: 16 x 32 hidden units (96 gate-cols)

// ---- ws layout (float element offsets) ----
#define OFF_HID    0u        // [512][512] hidden after first MLP layer
#define OFF_BASE   262144u   // [512][512] baseline
#define OFF_WHH0P  524288u   // [16][96][512] packed Whh0
#define OFF_WIH1P  1310720u  // [16][96][512] packed Wih1
#define OFF_WHH1P  2097152u  // [16][96][512] packed Whh1
#define OFF_WMIDP  2883584u  // [16][96][512] packed Wih0 rows 64..575
#define OFF_WTOPP  3670016u  // [16][96][64]  packed Wih0 rows 0..63
#define OFF_WTS    3768320u  // [16][96]      Wih0 row 576 (ts)
#define OFF_WIRR   3769856u  // [16][2][96]   Wih0 rows 577,578 (irr)
#define OFF_GI0S   3772928u  // [16][512][96] gi0 static part (baseline@Wmid + bih0)
#define OFF_H0     4559360u  // [2][512][512] h0 ping-pong
#define OFF_H1     5083648u  // [2][512][512] h1 ping-pong
#define OFF_IRR0   5607936u  // [512][2]
#define OFF_CTR    5608960u  // barrier counters (16 groups x 32 u32)
#define OFF_END    5609472u  // ~22.4 MB total

// ---- out layout (flat concat, reference return order) ----
#define OUT_SC   0u
#define OUT_SCAT 8192u
#define OUT_TC   20992u
#define OUT_TCAT 1593856u
#define OUT_VM   3035648u
#define OUT_VT   3101184u

__device__ __forceinline__ float sigm(float x) { return 1.0f / (1.0f + expf(-x)); }
__device__ __forceinline__ float gumb(float u) { return -logf(-logf(u + 1e-10f) + 1e-10f); }
// agent-scope (device) coherent accesses: bypass non-coherent per-XCD L2 so we
// never need acquire fences (which would buffer_inv the weight-resident L2).
__device__ __forceinline__ float aload(const float* p) {
  return __hip_atomic_load(p, __ATOMIC_RELAXED, __HIP_MEMORY_SCOPE_AGENT);
}
__device__ __forceinline__ void astore(float* p, float v) {
  __hip_atomic_store(p, v, __ATOMIC_RELAXED, __HIP_MEMORY_SCOPE_AGENT);
}

// ---------------- weight packing ----------------
// big matrices -> [s][c][k], c = 3*j_local + gate, so one thread owns r,z,n of one unit.
__global__ __launch_bounds__(256) void pack_kernel(
    const float* __restrict__ Wih0, const float* __restrict__ Whh0,
    const float* __restrict__ Wih1, const float* __restrict__ Whh1,
    float* __restrict__ ws) {
  int idx = blockIdx.x * 256 + threadIdx.x;
  const int BIG = 4 * 786432;
  if (idx < BIG) {
    int m = idx / 786432, r = idx % 786432;
    int s = r / 49152, c = (r / 512) % 96, k = r % 512;
    int col = (c % 3) * 512 + s * 32 + (c / 3);
    float v; unsigned dst;
    if (m == 0)      { v = Whh0[k * 1536 + col];        dst = OFF_WHH0P; }
    else if (m == 1) { v = Wih1[k * 1536 + col];        dst = OFF_WIH1P; }
    else if (m == 2) { v = Whh1[k * 1536 + col];        dst = OFF_WHH1P; }
    else             { v = Wih0[(64 + k) * 1536 + col]; dst = OFF_WMIDP; }
    ws[dst + r] = v;
    return;
  }
  idx -= BIG;
  if (idx < 98304) { // top: zt rows
    int s = idx / 6144, c = (idx / 64) % 96, k = idx % 64;
    ws[OFF_WTOPP + (unsigned)idx] = Wih0[k * 1536 + (c % 3) * 512 + s * 32 + (c / 3)];
    return;
  }
  idx -= 98304;
  if (idx < 1536) { // ts row (576)
    int s = idx / 96, c = idx % 96;
    ws[OFF_WTS + (unsigned)idx] = Wih0[576 * 1536 + (c % 3) * 512 + s * 32 + (c / 3)];
    return;
  }
  idx -= 1536;
  if (idx < 3072) { // irr rows (577,578)
    int s = idx / 192, m = (idx % 192) / 96, c = idx % 96;
    ws[OFF_WIRR + (unsigned)idx] = Wih0[(577 + m) * 1536 + (c % 3) * 512 + s * 32 + (c / 3)];
  }
}

// ---------------- static MLP (relu(X@W+b)), N=512, 4 rows/block ----------------
template <int K>
__global__ __launch_bounds__(256) void mlp_kernel(
    const float* __restrict__ X, const float* __restrict__ Wm,
    const float* __restrict__ bias, float* __restrict__ Y) {
  __shared__ float Xs[4][K];
  const int rt = blockIdx.x, tid = threadIdx.x;
  for (int i = tid; i < 4 * K; i += 256) Xs[i / K][i % K] = X[(rt * 4 + i / K) * K + (i % K)];
  __syncthreads();
  float acc[4][2] = {};
  const int c0 = tid, c1 = tid + 256;
  for (int k = 0; k < K; ++k) {
    float w0 = Wm[k * 512 + c0], w1 = Wm[k * 512 + c1];
#pragma unroll
    for (int r = 0; r < 4; ++r) {
      acc[r][0] = fmaf(Xs[r][k], w0, acc[r][0]);
      acc[r][1] = fmaf(Xs[r][k], w1, acc[r][1]);
    }
  }
#pragma unroll
  for (int r = 0; r < 4; ++r) {
    Y[(rt * 4 + r) * 512 + c0] = fmaxf(acc[r][0] + bias[c0], 0.0f);
    Y[(rt * 4 + r) * 512 + c1] = fmaxf(acc[r][1] + bias[c1], 0.0f);
  }
}

// ---------------- gi0 static part: baseline @ Wih0[64:576] + bih0, packed ----------------
__global__ __launch_bounds__(256) void gi0_kernel(
    const float* __restrict__ baseline, const float* __restrict__ WmidP,
    const float* __restrict__ bih0, float* __restrict__ gi0s) {
  __shared__ float As[64][128];
  __shared__ float Bs[96][129];
  const int s = blockIdx.x >> 3, rt = blockIdx.x & 7;
  const int tid = threadIdx.x, cg = tid & 31, rg = tid >> 5;
  float acc[8][3] = {};
  for (int kc = 0; kc < 4; ++kc) {
    for (int i = tid; i < 2048; i += 256) {
      int r = i >> 5, k4 = (i & 31) << 2;
      *(float4*)&As[r][k4] = *(const float4*)&baseline[(rt * 64 + r) * 512 + kc * 128 + k4];
    }
    for (int i = tid; i < 3072; i += 256) {
      int c = i >> 5, k4 = (i & 31) << 2;
      float4 v = *(const float4*)&WmidP[((unsigned)s * 96 + c) * 512 + kc * 128 + k4];
      Bs[c][k4] = v.x; Bs[c][k4 + 1] = v.y; Bs[c][k4 + 2] = v.z; Bs[c][k4 + 3] = v.w;
    }
    __syncthreads();
    for (int kk = 0; kk < 128; ++kk) {
      float b0 = Bs[3 * cg + 0][kk], b1 = Bs[3 * cg + 1][kk], b2 = Bs[3 * cg + 2][kk];
#pragma unroll
      for (int r = 0; r < 8; ++r) {
        float a = As[rg * 8 + r][kk];
        acc[r][0] = fmaf(a, b0, acc[r][0]);
        acc[r][1] = fmaf(a, b1, acc[r][1]);
        acc[r][2] = fmaf(a, b2, acc[r][2]);
      }
    }
    __syncthreads();
  }
#pragma unroll
  for (int r = 0; r < 8; ++r)
#pragma unroll
    for (int j = 0; j < 3; ++j) {
      int c = 3 * cg + j;
      gi0s[((unsigned)s * 512 + rt * 64 + rg * 8 + r) * 96 + c] = acc[r][j] + bih0[j * 512 + s * 32 + cg];
    }
}

// ---------------- static heads: static_cont, static_cat, irr0 ----------------
__device__ void gumbel_write(const float* logits, int w, const float* u, float* dst) {
  float e[12]; float mx = -1e30f;
#pragma unroll
  for (int i = 0; i < 12; ++i) if (i < w) { e[i] = logits[i] + gumb(u[i]); mx = fmaxf(mx, e[i]); }
  float sum = 0.0f;
#pragma unroll
  for (int i = 0; i < 12; ++i) if (i < w) { e[i] = expf(e[i] - mx); sum += e[i]; }
  float inv = 1.0f / sum;
#pragma unroll
  for (int i = 0; i < 12; ++i) if (i < w) dst[i] = e[i] * inv;
}

__global__ __launch_bounds__(64) void static_heads_kernel(
    const float* __restrict__ baseline,
    const float* __restrict__ W_sc, const float* __restrict__ b_sc,
    const float* __restrict__ W_cat0, const float* __restrict__ b_cat0,
    const float* __restrict__ W_cat1, const float* __restrict__ b_cat1,
    const float* __restrict__ W_cat2, const float* __restrict__ b_cat2,
    const float* __restrict__ W_irr, const float* __restrict__ b_irr,
    const float* __restrict__ u_sc0, const float* __restrict__ u_sc1,
    const float* __restrict__ u_sc2, const float* __restrict__ u_irr,
    float* __restrict__ out, float* __restrict__ irr0buf) {
  const int b = blockIdx.x, tid = threadIdx.x;
  __shared__ float br[512];
  __shared__ float dots[48];
  for (int i = tid; i < 512; i += 64) br[i] = baseline[b * 512 + i];
  __syncthreads();
  if (tid < 45) {
    float d = 0.0f;
    if (tid < 16) { for (int k = 0; k < 512; ++k) d = fmaf(br[k], W_sc[k * 16 + tid], d); d += b_sc[tid]; }
    else if (tid < 24) { int c = tid - 16; for (int k = 0; k < 512; ++k) d = fmaf(br[k], W_cat0[k * 8 + c], d); d += b_cat0[c]; }
    else if (tid < 29) { int c = tid - 24; for (int k = 0; k < 512; ++k) d = fmaf(br[k], W_cat1[k * 5 + c], d); d += b_cat1[c]; }
    else if (tid < 41) { int c = tid - 29; for (int k = 0; k < 512; ++k) d = fmaf(br[k], W_cat2[k * 12 + c], d); d += b_cat2[c]; }
    else { int i = tid - 41, j = i >> 1, cls = i & 1;
           for (int k = 0; k < 512; ++k) d = fmaf(br[k], W_irr[j * 1024 + k * 2 + cls], d);
           d += b_irr[j * 2 + cls]; }
    dots[tid] = d;
  }
  __syncthreads();
  if (tid < 16) out[OUT_SC + b * 16 + tid] = sigm(dots[tid]);
  else if (tid == 16) gumbel_write(&dots[16], 8,  u_sc0 + b * 8,  out + OUT_SCAT + b * 25 + 0);
  else if (tid == 17) gumbel_write(&dots[24], 5,  u_sc1 + b * 5,  out + OUT_SCAT + b * 25 + 8);
  else if (tid == 18) gumbel_write(&dots[29], 12, u_sc2 + b * 12, out + OUT_SCAT + b * 25 + 13);
  else if (tid == 19 || tid == 20) {
    int j = tid - 19;
    float e0 = dots[41 + 2 * j] + gumb(u_irr[j * 1024 + b * 2 + 0]);
    float e1 = dots[42 + 2 * j] + gumb(u_irr[j * 1024 + b * 2 + 1]);
    float mx = fmaxf(e0, e1);
    float x0 = expf(e0 - mx), x1 = expf(e1 - mx);
    irr0buf[b * 2 + j] = x1 / (x0 + x1);
  }
}

// ---------------- persistent recurrence kernel ----------------
// 256 wgs = 16 groups (32 batch rows) x 16 slices (32 hidden units -> 96 gate cols).
// slice = blockIdx%16 so same-slice wgs share an XCD (round-robin dispatch) ->
// packed weight slices stay L2-resident. 2 group barriers per step.
__global__ __launch_bounds__(256, 1) void recurrence_kernel(
    float* ws, const float* __restrict__ z_temporal, const int* __restrict__ lengths,
    const float* __restrict__ bhh0, const float* __restrict__ bih1, const float* __restrict__ bhh1,
    const float* __restrict__ W_tc, const float* __restrict__ b_tc,
    const float* __restrict__ W_hz, const float* __restrict__ b_hz,
    const float* __restrict__ W_tcat0, const float* __restrict__ b_tcat0,
    const float* __restrict__ W_tcat2, const float* __restrict__ b_tcat2,
    const float* __restrict__ W_tcat4, const float* __restrict__ b_tcat4,
    const float* __restrict__ u_t0, const float* __restrict__ u_t2,
    const float* __restrict__ u_t4, const float* __restrict__ u_bern,
    float* __restrict__ out) {
  const int tid = threadIdx.x;
  const int s = blockIdx.x & 15;
  const int g = blockIdx.x >> 4;
  const int b0 = g * 32;
  const int cg = tid & 31;       // hidden-unit (j) within slice; owns cols 3cg..3cg+2
  const int rg = tid >> 5;       // row group: rows 4rg..4rg+3
  const int r0 = rg * 4;
  const int jglob = s * 32 + cg;

  __shared__ float Ah[32][516];  // staged A rows (pad 516: 4-way worst on phase-3 dots)
  __shared__ float Bt[96][129];  // weight chunk, [c][k] stride 129 -> conflict-free reads
  __shared__ float Az[32][64];   // zt rows for this step
  __shared__ float irr_l[32][2];
  __shared__ float logits_l[32][10];

  float* h0buf = ws + OFF_H0;
  float* h1buf = ws + OFF_H1;
  unsigned* ctr = ((unsigned*)(ws + OFF_CTR)) + g * 32;

  const float* WpA  = ws + OFF_WHH0P + (unsigned)s * 49152;
  const float* WpI  = ws + OFF_WIH1P + (unsigned)s * 49152;
  const float* WpH  = ws + OFF_WHH1P + (unsigned)s * 49152;
  const float* WpT  = ws + OFF_WTOPP + (unsigned)s * 6144;
  const float* wts  = ws + OFF_WTS + s * 96;
  const float* wirr = ws + OFF_WIRR + s * 192;
  const float* gi0s = ws + OFF_GI0S + ((unsigned)s * 512 + b0) * 96;

  if (tid < 64) irr_l[tid >> 1][tid & 1] = ws[OFF_IRR0 + (b0 + (tid >> 1)) * 2 + (tid & 1)];
  unsigned bar = 0;

  auto stageA = [&](const float* src) {
    __syncthreads();             // protect Ah from still-active readers
    for (int i = tid; i < 4096; i += 256) {
      int r = i >> 7, k4 = (i & 127) << 2;
      const float* p = src + r * 512 + k4;
      float4 v; v.x = aload(p); v.y = aload(p + 1); v.z = aload(p + 2); v.w = aload(p + 3);
      *(float4*)&Ah[r][k4] = v;
    }
    __syncthreads();
  };

  auto gemmK512 = [&](const float* Bp, float (&acc)[4][3]) {
    for (int kc = 0; kc < 4; ++kc) {
      for (int i = tid; i < 3072; i += 256) {
        int c = i >> 5, k4 = (i & 31) << 2;
        float4 v = *(const float4*)(Bp + (unsigned)c * 512 + kc * 128 + k4);
        Bt[c][k4] = v.x; Bt[c][k4 + 1] = v.y; Bt[c][k4 + 2] = v.z; Bt[c][k4 + 3] = v.w;
      }
      __syncthreads();
      const int kb = kc * 128;
      for (int kk = 0; kk < 128; kk += 4) {
        float a[4][4];
#pragma unroll
        for (int r = 0; r < 4; ++r) *(float4*)a[r] = *(const float4*)&Ah[r0 + r][kb + kk];
#pragma unroll
        for (int i = 0; i < 4; ++i) {
          float bv0 = Bt[3 * cg + 0][kk + i];
          float bv1 = Bt[3 * cg + 1][kk + i];
          float bv2 = Bt[3 * cg + 2][kk + i];
#pragma unroll
          for (int r = 0; r < 4; ++r) {
            acc[r][0] = fmaf(a[r][i], bv0, acc[r][0]);
            acc[r][1] = fmaf(a[r][i], bv1, acc[r][1]);
            acc[r][2] = fmaf(a[r][i], bv2, acc[r][2]);
          }
        }
      }
      __syncthreads();
    }
  };

  auto gemmK64 = [&](const float* Bp, float (&acc)[4][3]) {
    for (int i = tid; i < 1536; i += 256) {
      int c = i >> 4, k4 = (i & 15) << 2;
      float4 v = *(const float4*)(Bp + c * 64 + k4);
      Bt[c][k4] = v.x; Bt[c][k4 + 1] = v.y; Bt[c][k4 + 2] = v.z; Bt[c][k4 + 3] = v.w;
    }
    __syncthreads();
    for (int kk = 0; kk < 64; kk += 4) {
      float a[4][4];
#pragma unroll
      for (int r = 0; r < 4; ++r) *(float4*)a[r] = *(const float4*)&Az[r0 + r][kk];
#pragma unroll
      for (int i = 0; i < 4; ++i) {
        float bv0 = Bt[3 * cg + 0][kk + i];
        float bv1 = Bt[3 * cg + 1][kk + i];
        float bv2 = Bt[3 * cg + 2][kk + i];
#pragma unroll
        for (int r = 0; r < 4; ++r) {
          acc[r][0] = fmaf(a[r][i], bv0, acc[r][0]);
          acc[r][1] = fmaf(a[r][i], bv1, acc[r][1]);
          acc[r][2] = fmaf(a[r][i], bv2, acc[r][2]);
        }
      }
    }
    __syncthreads();
  };

  auto gbar = [&]() {
    __builtin_amdgcn_s_waitcnt(0);   // every wave drains its own stores pre-barrier
    __syncthreads();
    if (tid == 0) {
      bar += 16;
      __hip_atomic_fetch_add(ctr, 1u, __ATOMIC_RELEASE, __HIP_MEMORY_SCOPE_AGENT);
      while (__hip_atomic_load(ctr, __ATOMIC_RELAXED, __HIP_MEMORY_SCOPE_AGENT) < bar)
        __builtin_amdgcn_s_sleep(2);
    }
    __syncthreads();
    __asm__ __volatile__("" ::: "memory");
  };

  for (int t = 0; t < 128; ++t) {
    const int p = t & 1;
    const float tsv = (float)t * (1.0f / 127.0f);
    const float* h0rd = h0buf + p * 262144;
    float* h0wr = h0buf + (p ^ 1) * 262144;
    const float* h1rd = h1buf + p * 262144;
    float* h1wr = h1buf + (p ^ 1) * 262144;

    // ---- phase 1: gh0 = h0_prev@Whh0 ; gi0 = precomp + zt@Wtop + ts + irr ; cell0 ----
    for (int i = tid; i < 512; i += 256) {  // stage zt rows (plain cached loads)
      int r = i >> 4, k4 = (i & 15) << 2;
      *(float4*)&Az[r][k4] = *(const float4*)&z_temporal[((unsigned)(b0 + r) * 128 + t) * 64 + k4];
    }
    stageA(h0rd + b0 * 512);
    float accI[4][3] = {}; float accH[4][3] = {};
    gemmK512(WpA, accH);
    gemmK64(WpT, accI);
#pragma unroll
    for (int r = 0; r < 4; ++r) {
      const int lr = r0 + r;
      const int brow = b0 + lr;
      float i0 = irr_l[lr][0], i1 = irr_l[lr][1];
      int c0 = 3 * cg;
      float gir = accI[r][0] + gi0s[lr * 96 + c0 + 0] + tsv * wts[c0 + 0] + i0 * wirr[c0 + 0] + i1 * wirr[96 + c0 + 0];
      float giz = accI[r][1] + gi0s[lr * 96 + c0 + 1] + tsv * wts[c0 + 1] + i0 * wirr[c0 + 1] + i1 * wirr[96 + c0 + 1];
      float gin = accI[r][2] + gi0s[lr * 96 + c0 + 2] + tsv * wts[c0 + 2] + i0 * wirr[c0 + 2] + i1 * wirr[96 + c0 + 2];
      float ghr = accH[r][0] + bhh0[jglob];
      float ghz = accH[r][1] + bhh0[512 + jglob];
      float ghn = accH[r][2] + bhh0[1024 + jglob];
      float rr = sigm(gir + ghr);
      float zz = sigm(giz + ghz);
      float nn = tanhf(gin + rr * ghn);
      float hp = Ah[lr][jglob];
      astore(h0wr + (unsigned)brow * 512 + jglob, (1.0f - zz) * nn + zz * hp);
    }
    gbar();

    // ---- phase 2: gi1 = h0_new@Wih1 ; gh1 = h1_prev@Whh1 ; cell1 ----
#pragma unroll
    for (int r = 0; r < 4; ++r) { accI[r][0] = accI[r][1] = accI[r][2] = 0.0f;
                                  accH[r][0] = accH[r][1] = accH[r][2] = 0.0f; }
    stageA(h0wr + b0 * 512);
    gemmK512(WpI, accI);
    stageA(h1rd + b0 * 512);
    gemmK512(WpH, accH);
#pragma unroll
    for (int r = 0; r < 4; ++r) {
      const int lr = r0 + r;
      const int brow = b0 + lr;
      float gir = accI[r][0] + bih1[jglob];
      float giz = accI[r][1] + bih1[512 + jglob];
      float gin = accI[r][2] + bih1[1024 + jglob];
      float ghr = accH[r][0] + bhh1[jglob];
      float ghz = accH[r][1] + bhh1[512 + jglob];
      float ghn = accH[r][2] + bhh1[1024 + jglob];
      float rr = sigm(gir + ghr);
      float zz = sigm(giz + ghz);
      float nn = tanhf(gin + rr * ghn);
      float hp = Ah[lr][jglob];
      astore(h1wr + (unsigned)brow * 512 + jglob, (1.0f - zz) * nn + zz * hp);
    }
    gbar();

    // ---- phase 3: heads from h1_new; replicated haz/irr update ----
    stageA(h1wr + b0 * 512);
    if (tid < 64) {
      int r = tid >> 1, m = tid & 1;
      const float* whz = W_hz + m * 513;
      float d = 0.0f;
      for (int k = 0; k < 512; ++k) d = fmaf(Ah[r][k], whz[k], d);
      d += tsv * whz[512] + b_hz[m];
      float haz = sigm(d);
      float iold = irr_l[r][m];
      float ub = u_bern[((unsigned)t * 512 + b0 + r) * 2 + m];
      float flip = (ub < haz * (1.0f - iold)) ? 1.0f : 0.0f;
      irr_l[r][m] = fminf(iold + flip, 1.0f);   // each thread owns its (r,m)
    }
    __syncthreads();

    if (s < 12) {
      if (tid < 64) {
        int r = tid >> 1, cl = tid & 1, col = 2 * s + cl;
        float d = 0.0f;
        for (int k = 0; k < 512; ++k) d = fmaf(Ah[r][k], W_tc[k * 24 + col], d);
        int brow = b0 + r;
        float msk = (t < lengths[brow]) ? 1.0f : 0.0f;
        out[OUT_TC + ((unsigned)brow * 128 + t) * 24 + col] = sigm(d + b_tc[col]) * msk;
      }
    } else if (s == 15) {
      if (tid < 64) {
        int r = tid >> 1, m = tid & 1, brow = b0 + r;
        float msk = (t < lengths[brow]) ? 1.0f : 0.0f;
        out[OUT_TCAT + ((unsigned)brow * 128 + t) * 22 + (m ? 17 : 6)] = irr_l[r][m] * msk;
        if (m == 0) {
          out[OUT_VM + (unsigned)brow * 128 + t] = msk;
          out[OUT_VT + (unsigned)brow * 128 + t] = tsv;
        }
      }
    } else {
      const int w = (s == 12) ? 6 : (s == 13) ? 10 : 4;
      const float* Wt = (s == 12) ? W_tcat0 : (s == 13) ? W_tcat2 : W_tcat4;
      const float* bt = (s == 12) ? b_tcat0 : (s == 13) ? b_tcat2 : b_tcat4;
      const float* ut = (s == 12) ? u_t0 : (s == 13) ? u_t2 : u_t4;
      const int cbase = (s == 12) ? 0 : (s == 13) ? 7 : 18;
      for (int q = tid; q < 32 * w; q += 256) {
        int r = q / w, cl = q % w;
        float d = 0.0f;
        for (int k = 0; k < 512; ++k) d = fmaf(Ah[r][k], Wt[k * w + cl], d);
        logits_l[r][cl] = d + bt[cl];
      }
      __syncthreads();   // wg-uniform branch (s uniform per wg)
      if (tid < 32) {
        int r = tid, brow = b0 + r;
        float msk = (t < lengths[brow]) ? 1.0f : 0.0f;
        float e[10]; float mx = -1e30f;
#pragma unroll
        for (int i = 0; i < 10; ++i) if (i < w) {
          float u = ut[((unsigned)t * 512 + brow) * (unsigned)w + i];
          e[i] = logits_l[r][i] + gumb(u);
          mx = fmaxf(mx, e[i]);
        }
        float sum = 0.0f;
#pragma unroll
        for (int i = 0; i < 10; ++i) if (i < w) { e[i] = expf(e[i] - mx); sum += e[i]; }
        float inv = 1.0f / sum;
#pragma unroll
        for (int i = 0; i < 10; ++i) if (i < w)
          out[OUT_TCAT + ((unsigned)brow * 128 + t) * 22 + cbase + i] = e[i] * inv * msk;
      }
    }
    // no barrier needed here: next phase-1 only reads data synced at barriers A/B,
    // and stageA's leading __syncthreads protects Ah.
  }
}

// ---------------- launcher ----------------
extern "C" void kernel_launch(void* const* d_in, const int* in_sizes, int n_in,
                              void* d_out, int out_size, void* d_ws, size_t ws_size,
                              hipStream_t stream) {
  const float* z_static   = (const float*)d_in[0];
  const float* z_temporal = (const float*)d_in[1];
  const int*   lengths    = (const int*)d_in[2];
  const float* Ws1 = (const float*)d_in[3];
  const float* bs1 = (const float*)d_in[4];
  const float* Ws2 = (const float*)d_in[5];
  const float* bs2 = (const float*)d_in[6];
  const float* W_sc = (const float*)d_in[7];
  const float* b_sc = (const float*)d_in[8];
  const float* W_cat0 = (const float*)d_in[9];
  const float* b_cat0 = (const float*)d_in[10];
  const float* W_cat1 = (const float*)d_in[11];
  const float* b_cat1 = (const float*)d_in[12];
  const float* W_cat2 = (const float*)d_in[13];
  const float* b_cat2 = (const float*)d_in[14];
  const float* W_irr = (const float*)d_in[15];
  const float* b_irr = (const float*)d_in[16];
  const float* Wih0 = (const float*)d_in[17];
  const float* Whh0 = (const float*)d_in[18];
  const float* bih0 = (const float*)d_in[19];
  const float* bhh0 = (const float*)d_in[20];
  const float* Wih1 = (const float*)d_in[21];
  const float* Whh1 = (const float*)d_in[22];
  const float* bih1 = (const float*)d_in[23];
  const float* bhh1 = (const float*)d_in[24];
  const float* W_tc = (const float*)d_in[25];
  const float* b_tc = (const float*)d_in[26];
  const float* W_tcat0 = (const float*)d_in[27];
  const float* b_tcat0 = (const float*)d_in[28];
  const float* W_tcat2 = (const float*)d_in[29];
  const float* b_tcat2 = (const float*)d_in[30];
  const float* W_tcat4 = (const float*)d_in[31];
  const float* b_tcat4 = (const float*)d_in[32];
  const float* W_hz = (const float*)d_in[33];
  const float* b_hz = (const float*)d_in[34];
  const float* u_sc0 = (const float*)d_in[35];
  const float* u_sc1 = (const float*)d_in[36];
  const float* u_sc2 = (const float*)d_in[37];
  const float* u_irr = (const float*)d_in[38];
  const float* u_t0 = (const float*)d_in[39];
  const float* u_t2 = (const float*)d_in[40];
  const float* u_t4 = (const float*)d_in[41];
  const float* u_bern = (const float*)d_in[42];

  float* ws = (float*)d_ws;
  float* out = (float*)d_out;

  // zero h ping-pong buffers + irr0 + barrier counters (d_ws is poisoned each call)
  hipMemsetAsync((void*)(ws + OFF_H0), 0, (size_t)(OFF_END - OFF_H0) * sizeof(float), stream);

  pack_kernel<<<12690, 256, 0, stream>>>(Wih0, Whh0, Wih1, Whh1, ws);
  mlp_kernel<128><<<128, 256, 0, stream>>>(z_static, Ws1, bs1, ws + OFF_HID);
  mlp_kernel<512><<<128, 256, 0, stream>>>(ws + OFF_HID, Ws2, bs2, ws + OFF_BASE);
  static_heads_kernel<<<512, 64, 0, stream>>>(ws + OFF_BASE, W_sc, b_sc,
      W_cat0, b_cat0, W_cat1, b_cat1, W_cat2, b_cat2, W_irr, b_irr,
      u_sc0, u_sc1, u_sc2, u_irr, out, ws + OFF_IRR0);
  gi0_kernel<<<128, 256, 0, stream>>>(ws + OFF_BASE, ws + OFF_WMIDP, bih0, ws + OFF_GI0S);
  recurrence_kernel<<<256, 256, 0, stream>>>(ws, z_temporal, lengths,
      bhh0, bih1, bhh1, W_tc, b_tc, W_hz, b_hz,
      W_tcat0, b_tcat0, W_tcat2, b_tcat2, W_tcat4, b_tcat4,
      u_t0, u_t2, u_t4, u_bern, out);
}